// Round 1
// baseline (127.545 us; speedup 1.0000x reference)
//
#include <hip/hip_runtime.h>
#include <math.h>

#define MDIM 512
#define NDIM 512
#define KDIM 512

#define BM 64
#define BN 64
#define BK 32
#define LSTR 68   // padded LDS row stride (floats), 16B-aligned rows, breaks bank patterns
#define KSPLIT 8

// ---------------------------------------------------------------------------
// Kernel 1: per-element SC encoding precompute.
//   ax = m * 2^e (frexp, m in [0.5,1))
//   q  = floor(m * L)                 (exact; dataWidth cancels)
//   vA = sign * 2^(e - log2 L), vB = sign * 2^e, zero-masked
// ---------------------------------------------------------------------------
__global__ void sc_precompute(const float* __restrict__ t1, const float* __restrict__ t2,
                              float* __restrict__ v1, float* __restrict__ q1,
                              float* __restrict__ v2, float* __restrict__ q2,
                              int nA, int nB, float Lf, int logL) {
    int i = blockIdx.x * blockDim.x + threadIdx.x;
    if (i >= nA + nB) return;
    bool isB = (i >= nA);
    int idx = isB ? (i - nA) : i;
    float x = isB ? t2[idx] : t1[idx];
    float ax = fabsf(x);
    float v = 0.0f, q = 0.0f;
    if (ax > 0.0f) {
        int e;
        float m = frexpf(ax, &e);      // ax = m * 2^e, m in [0.5, 1)
        q = floorf(m * Lf);            // in [L/2, L)
        float s = (x > 0.0f) ? 1.0f : -1.0f;
        int sh = isB ? e : (e - logL);
        v = ldexpf(s, sh);
    }
    if (isB) { v2[idx] = v; q2[idx] = q; }
    else     { v1[idx] = v; q1[idx] = q; }
}

// ---------------------------------------------------------------------------
// Kernel 2: zero the output (harness poisons d_out with 0xAA before each call)
// ---------------------------------------------------------------------------
__global__ void zero_out(float4* __restrict__ out, int n4) {
    int i = blockIdx.x * blockDim.x + threadIdx.x;
    if (i < n4) out[i] = make_float4(0.f, 0.f, 0.f, 0.f);
}

// ---------------------------------------------------------------------------
// Kernel 3: fused min-GEMM (approx) + f32 GEMM (exact), split-K with atomics.
//   approx[m,n] = sum_k v1*v2*min(q1,q2);  exact[m,n] = sum_k t1*t2
// Block: 16x16 threads, each computes a 4x4 micro-tile of a 64x64 block tile.
// Grid: (N/BN, M/BM, KSPLIT).
// ---------------------------------------------------------------------------
__global__ __launch_bounds__(256) void sc_gemm(
        const float* __restrict__ v1, const float* __restrict__ q1, const float* __restrict__ t1,
        const float* __restrict__ v2, const float* __restrict__ q2, const float* __restrict__ t2,
        float* __restrict__ out) {
    __shared__ __align__(16) float As_v[BK][LSTR];
    __shared__ __align__(16) float As_q[BK][LSTR];
    __shared__ __align__(16) float As_t[BK][LSTR];
    __shared__ __align__(16) float Bs_v[BK][LSTR];
    __shared__ __align__(16) float Bs_q[BK][LSTR];
    __shared__ __align__(16) float Bs_t[BK][LSTR];

    const int tid = threadIdx.x;
    const int tx = tid & 15;          // column group
    const int ty = tid >> 4;          // row group
    const int n0 = blockIdx.x * BN;
    const int m0 = blockIdx.y * BM;
    const int kbase = blockIdx.z * (KDIM / KSPLIT);   // 64-wide K chunk

    float acc[4][4] = {};
    float acce[4][4] = {};

    for (int kt = 0; kt < (KDIM / KSPLIT) / BK; ++kt) {   // 2 iterations
        const int kk0 = kbase + kt * BK;
        if (kt) __syncthreads();

        // stage A tile (64 rows x 32 k), transposed into LDS [k][m]
        #pragma unroll
        for (int ff = 0; ff < 2; ++ff) {
            int f = tid + ff * 256;            // 512 float4s per array
            int row = f >> 3;                  // 0..63
            int c4  = (f & 7) << 2;            // k offset 0..28
            int g = (m0 + row) * KDIM + kk0 + c4;
            float4 a = *(const float4*)(v1 + g);
            float4 b = *(const float4*)(q1 + g);
            float4 c = *(const float4*)(t1 + g);
            As_v[c4+0][row] = a.x; As_v[c4+1][row] = a.y; As_v[c4+2][row] = a.z; As_v[c4+3][row] = a.w;
            As_q[c4+0][row] = b.x; As_q[c4+1][row] = b.y; As_q[c4+2][row] = b.z; As_q[c4+3][row] = b.w;
            As_t[c4+0][row] = c.x; As_t[c4+1][row] = c.y; As_t[c4+2][row] = c.z; As_t[c4+3][row] = c.w;
        }
        // stage B tile (32 k x 64 cols), natural layout [k][n]
        #pragma unroll
        for (int ff = 0; ff < 2; ++ff) {
            int f = tid + ff * 256;
            int rowk = f >> 4;                 // 0..31
            int c4   = (f & 15) << 2;          // n offset 0..60
            int g = (kk0 + rowk) * NDIM + n0 + c4;
            *(float4*)&Bs_v[rowk][c4] = *(const float4*)(v2 + g);
            *(float4*)&Bs_q[rowk][c4] = *(const float4*)(q2 + g);
            *(float4*)&Bs_t[rowk][c4] = *(const float4*)(t2 + g);
        }
        __syncthreads();

        #pragma unroll 8
        for (int kk = 0; kk < BK; ++kk) {
            float av[4], aq[4], at[4], bv[4], bq[4], bt[4];
            *(float4*)av = *(const float4*)&As_v[kk][ty << 2];
            *(float4*)aq = *(const float4*)&As_q[kk][ty << 2];
            *(float4*)at = *(const float4*)&As_t[kk][ty << 2];
            *(float4*)bv = *(const float4*)&Bs_v[kk][tx << 2];
            *(float4*)bq = *(const float4*)&Bs_q[kk][tx << 2];
            *(float4*)bt = *(const float4*)&Bs_t[kk][tx << 2];
            #pragma unroll
            for (int i = 0; i < 4; ++i) {
                #pragma unroll
                for (int j = 0; j < 4; ++j) {
                    acc[i][j]  = fmaf(av[i] * bv[j], fminf(aq[i], bq[j]), acc[i][j]);
                    acce[i][j] = fmaf(at[i], bt[j], acce[i][j]);
                }
            }
        }
    }

    // epilogue: atomic accumulate (KSPLIT partial sums per output element)
    const int MN = MDIM * NDIM;
    #pragma unroll
    for (int i = 0; i < 4; ++i) {
        int m = m0 + (ty << 2) + i;
        #pragma unroll
        for (int j = 0; j < 4; ++j) {
            int n = n0 + (tx << 2) + j;
            unsafeAtomicAdd(&out[m * NDIM + n], acc[i][j]);
            unsafeAtomicAdd(&out[MN + m * NDIM + n], acce[i][j]);
        }
    }
}

extern "C" void kernel_launch(void* const* d_in, const int* in_sizes, int n_in,
                              void* d_out, int out_size, void* d_ws, size_t ws_size,
                              hipStream_t stream) {
    const float* t1 = (const float*)d_in[0];
    const float* t2 = (const float*)d_in[1];
    // d_in[2] = rngSeq (arange per spec -> thermometer code), d_in[3] = dataWidth (cancels)
    int L = in_sizes[2];
    int logL = 31 - __builtin_clz((unsigned)L);

    float* v1 = (float*)d_ws;
    float* q1 = v1 + MDIM * KDIM;
    float* v2 = q1 + MDIM * KDIM;
    float* q2 = v2 + KDIM * NDIM;
    float* out = (float*)d_out;

    int ntot = MDIM * KDIM + KDIM * NDIM;
    hipLaunchKernelGGL(sc_precompute, dim3((ntot + 255) / 256), dim3(256), 0, stream,
                       t1, t2, v1, q1, v2, q2, MDIM * KDIM, KDIM * NDIM, (float)L, logL);

    int n4 = out_size / 4;
    hipLaunchKernelGGL(zero_out, dim3((n4 + 255) / 256), dim3(256), 0, stream,
                       (float4*)out, n4);

    hipLaunchKernelGGL(sc_gemm, dim3(NDIM / BN, MDIM / BM, KSPLIT), dim3(256), 0, stream,
                       v1, q1, t1, v2, q2, t2, out);
}